// Round 6
// baseline (247.332 us; speedup 1.0000x reference)
//
#include <hip/hip_runtime.h>
#include <hip/hip_bf16.h>

// LSTM cell, B=8192, IN=1024, H=1024.
// gates[8192,4096] = [x|h_prev] @ [Wf|Wi|Wu|Wo] + b ; fused epilogue -> h_t, c_t.
// Round 6: B (weights) bypasses LDS -> loaded global->registers per slot
// (L2-resident, double-buffered one slot ahead). LDS carries A only (ring-4,
// 64 KB). Rationale: per-CU per-slot LDS demand (A+B reads ~1400cyc) was
// co-critical with MFMA (1242cyc) and they serialize CU-wide under lockstep
// barriers; offloading B drops LDS to ~900cyc < MFMA -> MFMA-bound.

typedef __attribute__((ext_vector_type(8))) short short8;   // 8 bf16
typedef __attribute__((ext_vector_type(4))) float f32x4;

#define GLOBAL_AS __attribute__((address_space(1)))
#define LDS_AS    __attribute__((address_space(3)))

__device__ __forceinline__ void load_lds16(const void* g, void* l) {
  // 16B/lane global->LDS DMA; LDS dest = wave-uniform base + lane*16 (linear)
  __builtin_amdgcn_global_load_lds((const GLOBAL_AS unsigned int*)g,
                                   (LDS_AS unsigned int*)l, 16, 0, 0);
}

__device__ __forceinline__ unsigned short f2bf(float f) {
  unsigned int u = __float_as_uint(f);
  return (unsigned short)((u + 0x7FFFu + ((u >> 16) & 1u)) >> 16);  // RNE
}
__device__ __forceinline__ float sigf(float x) { return 1.0f / (1.0f + __expf(-x)); }
__device__ __forceinline__ float tanh_fast(float x) {
  return 1.0f - 2.0f / (__expf(2.0f * x) + 1.0f);
}

// ---------------------------------------------------------------------------
// Merged pack kernel:
//  blocks [0, 8192):    A = [x | h_prev] -> bf16 Apk[8192][2048], linear
//  blocks [8192,12288): W^T -> bf16 Wp[4096][2048], Wp[n][k] = W_g[k][n']
// ---------------------------------------------------------------------------
__global__ void pack_kernel(const float* __restrict__ x,
                            const float* __restrict__ h,
                            const float* __restrict__ W0,
                            const float* __restrict__ W1,
                            const float* __restrict__ W2,
                            const float* __restrict__ W3,
                            unsigned short* __restrict__ Apk,
                            unsigned short* __restrict__ Wp) {
  int blk = blockIdx.x;
  if (blk < 8192) {
    int t = blk * 256 + threadIdx.x;
    int row = t >> 8;
    int c   = t & 255;
    int k   = c << 3;
    const float* src = (k < 1024) ? (x + (size_t)row * 1024 + k)
                                  : (h + (size_t)row * 1024 + (k - 1024));
    float4 f0 = ((const float4*)src)[0];
    float4 f1 = ((const float4*)src)[1];
    union { unsigned short us[8]; uint4 v; } u;
    u.us[0] = f2bf(f0.x); u.us[1] = f2bf(f0.y);
    u.us[2] = f2bf(f0.z); u.us[3] = f2bf(f0.w);
    u.us[4] = f2bf(f1.x); u.us[5] = f2bf(f1.y);
    u.us[6] = f2bf(f1.z); u.us[7] = f2bf(f1.w);
    *(uint4*)(Apk + (size_t)row * 2048 + c * 8) = u.v;
  } else {
    int b  = blk - 8192;
    int c  = b & 255;          // k-chunk
    int nb = (b >> 8) & 3;     // n' block
    int g  = b >> 10;          // gate
    const float* Wg = (g == 0) ? W0 : (g == 1) ? W1 : (g == 2) ? W2 : W3;
    int np = nb * 256 + threadIdx.x;
    int kbase = c << 3;
    union { unsigned short us[8]; uint4 v; } u;
#pragma unroll
    for (int j = 0; j < 8; ++j)
      u.us[j] = f2bf(Wg[(size_t)(kbase + j) * 1024 + np]);
    int n = (g << 10) + np;
    *(uint4*)(Wp + (size_t)n * 2048 + c * 8) = u.v;
  }
}

// ---------------------------------------------------------------------------
// GEMM + LSTM epilogue. B direct-to-register, A via LDS ring-4.
// Block: 512 thr = 8 waves (2M x 4N). Tile: 256 M x 256 packed cols
// (packed col p = (h>>4)*64 + g*16 + (h&15) -> wave holds 4 gates of same h).
// K=2048 -> 64 slots of K=32. LDS: A ring of 4 slots x 16 KB = 64 KB.
// Per slot per wave: 4 B global_load_dwordx4 (slot s+1) + 2 A-DMA (slot s+3)
// + 8 A ds_read_b128 + 32 MFMA + vmcnt(4) + 1 barrier.
// ---------------------------------------------------------------------------
#define MFMA16(va, vb, vc) __builtin_amdgcn_mfma_f32_16x16x32_bf16(va, vb, vc, 0, 0, 0)

// S: slot index; BCUR: b-frags for slot S (loaded last slot); BNXT: filled
// with slot S+1's b-frags.
#define SLOT(S, BCUR, BNXT)                                                    \
  {                                                                            \
    const int ring_ = ((S) & 3) * 8192;                                        \
    {                                                                          \
      int sn_ = (S) + 1; sn_ = sn_ > 63 ? 63 : sn_;                            \
      _Pragma("unroll")                                                        \
      for (int gg = 0; gg < 4; ++gg)                                           \
        BNXT[gg] = *(const short8*)(bSrcG[gg] + sn_ * 32);                     \
    }                                                                          \
    {                                                                          \
      int sp_ = (S) + 3; sp_ = sp_ > 63 ? 63 : sp_;                            \
      const int pr_ = ((S) + 3) & 3;                                           \
      load_lds16(aSrc0 + sp_ * 32, &LDSu[pr_ * 8192 + wv * 512]);              \
      load_lds16(aSrc1 + sp_ * 32, &LDSu[pr_ * 8192 + 4096 + wv * 512]);       \
    }                                                                          \
    {                                                                          \
      short8 av[4];                                                            \
      _Pragma("unroll")                                                        \
      for (int mm = 0; mm < 4; ++mm)                                           \
        av[mm] = *(const short8*)&LDSu[ring_ + aRdBase + mm * 512];            \
      __builtin_amdgcn_s_setprio(1);                                           \
      _Pragma("unroll")                                                        \
      for (int mm = 0; mm < 4; ++mm) {                                         \
        _Pragma("unroll")                                                      \
        for (int gg = 0; gg < 4; ++gg)                                         \
          acc[mm][gg] = MFMA16(av[mm], BCUR[gg], acc[mm][gg]);                 \
      }                                                                        \
      __builtin_amdgcn_s_setprio(0);                                           \
      _Pragma("unroll")                                                        \
      for (int mm = 0; mm < 4; ++mm)                                           \
        av[mm] = *(const short8*)&LDSu[ring_ + aRdBase + (4 + mm) * 512];      \
      __builtin_amdgcn_s_setprio(1);                                           \
      _Pragma("unroll")                                                        \
      for (int mm = 0; mm < 4; ++mm) {                                         \
        _Pragma("unroll")                                                      \
        for (int gg = 0; gg < 4; ++gg)                                         \
          acc[4 + mm][gg] = MFMA16(av[mm], BCUR[gg], acc[4 + mm][gg]);         \
      }                                                                        \
      __builtin_amdgcn_s_setprio(0);                                           \
    }                                                                          \
    asm volatile("s_waitcnt vmcnt(4)");                                        \
    __builtin_amdgcn_s_barrier();                                              \
  }

__global__ __launch_bounds__(512, 2) void lstm_gemm_kernel(
    const unsigned short* __restrict__ Apk,   // [8192][2048] bf16
    const unsigned short* __restrict__ Wp,    // [4096][2048] bf16 (W^T)
    const float* __restrict__ c_prev,
    const float* __restrict__ bF, const float* __restrict__ bI,
    const float* __restrict__ bU, const float* __restrict__ bO,
    float* __restrict__ outH, float* __restrict__ outC) {
  __shared__ __align__(16) unsigned short LDSu[32768];   // 64 KB, A ring only

  const int tid = threadIdx.x;
  const int l   = tid & 63;
  const int wv  = tid >> 6;        // wave 0..7
  const int wr  = wv >> 2;         // wave M index 0..1
  const int wc  = wv & 3;          // wave N index 0..3

  // XCD-bijective swizzle: 512 blocks = 8 XCDs x 64
  int bid = blockIdx.x;
  int wg  = ((bid & 7) << 6) | (bid >> 3);
  const int mblk = wg >> 4;        // 0..31
  const int nblk = wg & 15;        // 0..15
  const int brow = mblk << 8;      // M base (x256)

  // --- A ds_read addressing (ushort units). Rows are 32 us (one K-slot).
  // swizzled chunk sc = cg ^ ((row>>1)&3); 2-way bank aliasing only (free).
  const int rl  = l & 15;
  const int cg  = l >> 4;                       // k-chunk group 0..3
  const int sc  = cg ^ ((rl >> 1) & 3);
  const int aRdBase = (wr * 128 + rl) * 32 + sc * 8;

  // --- A staging source: LDS row = qq*128 + wv*16 + (l>>2), linear dest;
  // global source chunk = (l&3) ^ ((ldsrow>>1)&3) = (l&3)^((l>>3)&3).
  const int srow = wv * 16 + (l >> 2);          // 0..127 (qq=0 half)
  const int csw  = ((l & 3) ^ ((l >> 3) & 3)) * 8;
  const unsigned short* aSrc0 = Apk + (size_t)(brow + srow) * 2048 + csw;
  const unsigned short* aSrc1 = aSrc0 + (size_t)128 * 2048;

  // --- B direct-load addressing: frag g, lane l -> packed col
  // p = nblk*256 + wc*64 + g*16 + rl ; Wp row n = g(p)*1024 + h(p);
  // 16B at k-offset s*32 + cg*8. (Linear Wp; no swizzle needed for regs.)
  const unsigned short* bSrcG[4];
#pragma unroll
  for (int g = 0; g < 4; ++g) {
    int p = nblk * 256 + wc * 64 + g * 16 + rl;
    int n = (((p >> 4) & 3) << 10) | ((p >> 6) << 4) | (p & 15);
    bSrcG[g] = Wp + (size_t)n * 2048 + cg * 8;
  }

  f32x4 acc[8][4];                 // [m-frag][gate]
#pragma unroll
  for (int m = 0; m < 8; ++m)
#pragma unroll
    for (int g = 0; g < 4; ++g) acc[m][g] = (f32x4)0.0f;

  short8 bEven[4], bOdd[4];

  // --- prologue: B(0) -> bEven; stage A slots 0,1,2 into rings 0,1,2
#pragma unroll
  for (int g = 0; g < 4; ++g)
    bEven[g] = *(const short8*)(bSrcG[g] + 0);
#pragma unroll
  for (int s = 0; s < 3; ++s) {
    load_lds16(aSrc0 + s * 32, &LDSu[s * 8192 + wv * 512]);
    load_lds16(aSrc1 + s * 32, &LDSu[s * 8192 + 4096 + wv * 512]);
  }
  asm volatile("s_waitcnt vmcnt(4)");   // B(0) + A slot0 landed; A1,A2 in flight
  __builtin_amdgcn_s_barrier();

  // --- main loop: 2 slots per iteration (static b-frag double buffer)
#pragma unroll 1
  for (int u = 0; u < 32; ++u) {
    const int s0 = 2 * u;
    SLOT(s0,     bEven, bOdd)
    SLOT(s0 + 1, bOdd,  bEven)
  }

  // --- epilogue (register-local LSTM): frag g == gate g for the same h-col.
  const int colh = nblk * 64 + wc * 16 + rl;
  const float biasF = bF[colh], biasI = bI[colh];
  const float biasU = bU[colh], biasO = bO[colh];
  const int row0 = brow + wr * 128 + ((l >> 4) << 2);
#pragma unroll
  for (int m = 0; m < 8; ++m) {
#pragma unroll
    for (int r = 0; r < 4; ++r) {
      int row = row0 + m * 16 + r;
      size_t idx = (size_t)row * 1024 + colh;
      float f  = sigf(acc[m][0][r] + biasF);
      float i_ = sigf(acc[m][1][r] + biasI);
      float g_ = tanh_fast(acc[m][2][r] + biasU);
      float o_ = sigf(acc[m][3][r] + biasO);
      float cp = c_prev[idx];
      float cn = cp * f + i_ * g_;
      outH[idx] = o_ * tanh_fast(cn);
      outC[idx] = cn;
    }
  }
}

// ---------------------------------------------------------------------------
extern "C" void kernel_launch(void* const* d_in, const int* in_sizes, int n_in,
                              void* d_out, int out_size, void* d_ws, size_t ws_size,
                              hipStream_t stream) {
  const float* x      = (const float*)d_in[0];
  const float* h_prev = (const float*)d_in[1];
  const float* c_prev = (const float*)d_in[2];
  // d_in[3] = embed (unused by reference forward)
  const float* Wf = (const float*)d_in[4];
  const float* bf = (const float*)d_in[5];
  const float* Wi = (const float*)d_in[6];
  const float* bi = (const float*)d_in[7];
  const float* Wu = (const float*)d_in[8];
  const float* bu = (const float*)d_in[9];
  const float* Wo = (const float*)d_in[10];
  const float* bo = (const float*)d_in[11];

  unsigned short* Apk = (unsigned short*)d_ws;                                    // 32 MB
  unsigned short* Wp  = (unsigned short*)((char*)d_ws + (size_t)8192 * 2048 * 2); // 16 MB

  pack_kernel<<<12288, 256, 0, stream>>>(x, h_prev, Wf, Wi, Wu, Wo, Apk, Wp);

  float* outH = (float*)d_out;
  float* outC = outH + (size_t)8192 * 1024;
  lstm_gemm_kernel<<<512, 512, 0, stream>>>(Apk, Wp, c_prev,
                                            bf, bi, bu, bo, outH, outC);
}

// Round 7
// 176.992 us; speedup vs baseline: 1.3974x; 1.3974x over previous
//
#include <hip/hip_runtime.h>
#include <hip/hip_bf16.h>

// LSTM cell, B=8192, IN=1024, H=1024.
// gates[8192,4096] = [x|h_prev] @ [Wf|Wi|Wu|Wo] + b ; fused epilogue -> h_t, c_t.
// Round 7: B via FRAGMENT-PACKED global->reg loads (coalesced: lane l reads
// base + l*16B; fixes round 6's 64-line scatter). Wfrag[slot][p16][lane][16B]
// is exactly per-lane MFMA B-fragment order. LDS carries A only (ring-4,
// 64 KB). Per slot: 4 coalesced B loads (s+1) + 2 A-DMA (s+3) + 8 A ds_reads
// + 32 MFMA + vmcnt(2) + 1 barrier. vmcnt never 0 in the loop.

typedef __attribute__((ext_vector_type(8))) short short8;   // 8 bf16
typedef __attribute__((ext_vector_type(4))) float f32x4;

#define GLOBAL_AS __attribute__((address_space(1)))
#define LDS_AS    __attribute__((address_space(3)))

__device__ __forceinline__ void load_lds16(const void* g, void* l) {
  // 16B/lane global->LDS DMA; LDS dest = wave-uniform base + lane*16 (linear)
  __builtin_amdgcn_global_load_lds((const GLOBAL_AS unsigned int*)g,
                                   (LDS_AS unsigned int*)l, 16, 0, 0);
}

__device__ __forceinline__ unsigned short f2bf(float f) {
  unsigned int u = __float_as_uint(f);
  return (unsigned short)((u + 0x7FFFu + ((u >> 16) & 1u)) >> 16);  // RNE
}
__device__ __forceinline__ float sigf(float x) { return 1.0f / (1.0f + __expf(-x)); }
__device__ __forceinline__ float tanh_fast(float x) {
  return 1.0f - 2.0f / (__expf(2.0f * x) + 1.0f);
}

// ---------------------------------------------------------------------------
// Merged pack kernel:
//  blocks [0, 8192):    A = [x | h_prev] -> bf16 Apk[8192][2048], linear
//  blocks [8192,12288): W -> Wfrag[slot 64][p16 256][lane 64][8 bf16]
//    fragment-packed B: for (s, p16, l): g = p16&3, h = (p16>>2)*16 + (l&15),
//    k = s*32 + (l>>4)*8 + e  ->  value = W_g[k][h].
// ---------------------------------------------------------------------------
__global__ void pack_kernel(const float* __restrict__ x,
                            const float* __restrict__ h,
                            const float* __restrict__ W0,
                            const float* __restrict__ W1,
                            const float* __restrict__ W2,
                            const float* __restrict__ W3,
                            unsigned short* __restrict__ Apk,
                            unsigned short* __restrict__ Wfrag) {
  int blk = blockIdx.x;
  if (blk < 8192) {
    int t = blk * 256 + threadIdx.x;
    int row = t >> 8;
    int c   = t & 255;
    int k   = c << 3;
    const float* src = (k < 1024) ? (x + (size_t)row * 1024 + k)
                                  : (h + (size_t)row * 1024 + (k - 1024));
    float4 f0 = ((const float4*)src)[0];
    float4 f1 = ((const float4*)src)[1];
    union { unsigned short us[8]; uint4 v; } u;
    u.us[0] = f2bf(f0.x); u.us[1] = f2bf(f0.y);
    u.us[2] = f2bf(f0.z); u.us[3] = f2bf(f0.w);
    u.us[4] = f2bf(f1.x); u.us[5] = f2bf(f1.y);
    u.us[6] = f2bf(f1.z); u.us[7] = f2bf(f1.w);
    *(uint4*)(Apk + (size_t)row * 2048 + c * 8) = u.v;
  } else {
    // thread -> one 8-element B fragment slice
    int gt  = (blk - 8192) * 256 + threadIdx.x;   // 0 .. 1048575
    int l   = gt & 63;
    int p16 = (gt >> 6) & 255;
    int s   = gt >> 14;                           // 0..63
    int g   = p16 & 3;
    int hcol = ((p16 >> 2) << 4) + (l & 15);
    int k0  = s * 32 + (l >> 4) * 8;
    const float* Wg = (g == 0) ? W0 : (g == 1) ? W1 : (g == 2) ? W2 : W3;
    union { unsigned short us[8]; uint4 v; } u;
#pragma unroll
    for (int j = 0; j < 8; ++j)
      u.us[j] = f2bf(Wg[(size_t)(k0 + j) * 1024 + hcol]);
    *(uint4*)(Wfrag + (size_t)gt * 8) = u.v;
  }
}

// ---------------------------------------------------------------------------
// GEMM + LSTM epilogue. B fragment-packed -> regs; A via LDS ring-4.
// Block: 512 thr = 8 waves (2M x 4N). Tile: 256 M x 256 packed cols
// (packed col p = (h>>4)*64 + g*16 + (h&15) -> wave holds 4 gates of same h).
// K=2048 -> 64 slots of K=32. LDS: A ring of 4 slots x 16 KB = 64 KB.
// ---------------------------------------------------------------------------
#define MFMA16(va, vb, vc) __builtin_amdgcn_mfma_f32_16x16x32_bf16(va, vb, vc, 0, 0, 0)

// S: slot; BCUR: b-frags for slot S (loaded last slot); BNXT: filled with S+1.
#define SLOT(S, BCUR, BNXT)                                                    \
  {                                                                            \
    const int ring_ = ((S) & 3) * 8192;                                        \
    {                                                                          \
      int sn_ = (S) + 1; sn_ = sn_ > 63 ? 63 : sn_;                            \
      const unsigned short* bp_ = bBase + (size_t)sn_ * 131072;                \
      _Pragma("unroll")                                                        \
      for (int gg = 0; gg < 4; ++gg)                                           \
        BNXT[gg] = *(const short8*)(bp_ + gg * 512);                           \
    }                                                                          \
    {                                                                          \
      int sp_ = (S) + 3; sp_ = sp_ > 63 ? 63 : sp_;                            \
      const int pr_ = (((S) + 3) & 3) * 8192;                                  \
      load_lds16(aSrc0 + sp_ * 32, &LDSu[pr_ + wv * 512]);                     \
      load_lds16(aSrc1 + sp_ * 32, &LDSu[pr_ + 4096 + wv * 512]);              \
    }                                                                          \
    {                                                                          \
      short8 av[4];                                                            \
      _Pragma("unroll")                                                        \
      for (int mm = 0; mm < 4; ++mm)                                           \
        av[mm] = *(const short8*)&LDSu[ring_ + aRdBase + mm * 512];            \
      __builtin_amdgcn_s_setprio(1);                                           \
      _Pragma("unroll")                                                        \
      for (int mm = 0; mm < 4; ++mm) {                                         \
        _Pragma("unroll")                                                      \
        for (int gg = 0; gg < 4; ++gg)                                         \
          acc[mm][gg] = MFMA16(av[mm], BCUR[gg], acc[mm][gg]);                 \
      }                                                                        \
      __builtin_amdgcn_s_setprio(0);                                           \
      _Pragma("unroll")                                                        \
      for (int mm = 0; mm < 4; ++mm)                                           \
        av[mm] = *(const short8*)&LDSu[ring_ + aRdBase + (4 + mm) * 512];      \
      __builtin_amdgcn_s_setprio(1);                                           \
      _Pragma("unroll")                                                        \
      for (int mm = 0; mm < 4; ++mm) {                                         \
        _Pragma("unroll")                                                      \
        for (int gg = 0; gg < 4; ++gg)                                         \
          acc[4 + mm][gg] = MFMA16(av[mm], BCUR[gg], acc[4 + mm][gg]);         \
      }                                                                        \
      __builtin_amdgcn_s_setprio(0);                                           \
    }                                                                          \
    asm volatile("s_waitcnt vmcnt(2)");                                        \
    __builtin_amdgcn_s_barrier();                                              \
  }

__global__ __launch_bounds__(512, 2) void lstm_gemm_kernel(
    const unsigned short* __restrict__ Apk,     // [8192][2048] bf16
    const unsigned short* __restrict__ Wfrag,   // [64][256][64][8] bf16
    const float* __restrict__ c_prev,
    const float* __restrict__ bF, const float* __restrict__ bI,
    const float* __restrict__ bU, const float* __restrict__ bO,
    float* __restrict__ outH, float* __restrict__ outC) {
  __shared__ __align__(16) unsigned short LDSu[32768];   // 64 KB, A ring only

  const int tid = threadIdx.x;
  const int l   = tid & 63;
  const int wv  = tid >> 6;        // wave 0..7
  const int wr  = wv >> 2;         // wave M index 0..1
  const int wc  = wv & 3;          // wave N index 0..3

  // XCD-bijective swizzle: 512 blocks = 8 XCDs x 64
  int bid = blockIdx.x;
  int wg  = ((bid & 7) << 6) | (bid >> 3);
  const int mblk = wg >> 4;        // 0..31
  const int nblk = wg & 15;        // 0..15
  const int brow = mblk << 8;      // M base (x256)

  // --- A ds_read addressing (ushort units). Rows are 32 us (one K-slot).
  // swizzled chunk sc = cg ^ ((row>>1)&3); 2-way bank aliasing only (free).
  const int rl  = l & 15;
  const int cg  = l >> 4;                       // k-chunk group 0..3
  const int sc  = cg ^ ((rl >> 1) & 3);
  const int aRdBase = (wr * 128 + rl) * 32 + sc * 8;

  // --- A staging source: LDS row = qq*128 + wv*16 + (l>>2), linear dest;
  // global source chunk = (l&3) ^ ((ldsrow>>1)&3) = (l&3)^((l>>3)&3).
  const int srow = wv * 16 + (l >> 2);          // 0..127 (qq=0 half)
  const int csw  = ((l & 3) ^ ((l >> 3) & 3)) * 8;
  const unsigned short* aSrc0 = Apk + (size_t)(brow + srow) * 2048 + csw;
  const unsigned short* aSrc1 = aSrc0 + (size_t)128 * 2048;

  // --- B fragment base: p16base = nblk*16 + wc*4; lane-contiguous 16B.
  // slot stride = 256*64*8 = 131072 ushorts; frag g stride = 64*8 = 512.
  const unsigned short* bBase =
      Wfrag + ((size_t)(nblk * 16 + wc * 4) * 64 + l) * 8;

  f32x4 acc[8][4];                 // [m-frag][gate]
#pragma unroll
  for (int m = 0; m < 8; ++m)
#pragma unroll
    for (int g = 0; g < 4; ++g) acc[m][g] = (f32x4)0.0f;

  short8 bEven[4], bOdd[4];

  // --- prologue: B(0) -> bEven (4 loads); stage A slots 0,1,2 (6 DMAs)
#pragma unroll
  for (int g = 0; g < 4; ++g)
    bEven[g] = *(const short8*)(bBase + g * 512);
#pragma unroll
  for (int s = 0; s < 3; ++s) {
    load_lds16(aSrc0 + s * 32, &LDSu[s * 8192 + wv * 512]);
    load_lds16(aSrc1 + s * 32, &LDSu[s * 8192 + 4096 + wv * 512]);
  }
  asm volatile("s_waitcnt vmcnt(4)");   // B(0)+A0 landed; A1,A2 in flight
  __builtin_amdgcn_s_barrier();

  // --- main loop: 2 slots per iteration (static b-frag double buffer)
#pragma unroll 1
  for (int u = 0; u < 32; ++u) {
    const int s0 = 2 * u;
    SLOT(s0,     bEven, bOdd)
    SLOT(s0 + 1, bOdd,  bEven)
  }

  // --- epilogue (register-local LSTM): frag g == gate g for the same h-col.
  const int colh = nblk * 64 + wc * 16 + rl;
  const float biasF = bF[colh], biasI = bI[colh];
  const float biasU = bU[colh], biasO = bO[colh];
  const int row0 = brow + wr * 128 + ((l >> 4) << 2);
#pragma unroll
  for (int m = 0; m < 8; ++m) {
#pragma unroll
    for (int r = 0; r < 4; ++r) {
      int row = row0 + m * 16 + r;
      size_t idx = (size_t)row * 1024 + colh;
      float f  = sigf(acc[m][0][r] + biasF);
      float i_ = sigf(acc[m][1][r] + biasI);
      float g_ = tanh_fast(acc[m][2][r] + biasU);
      float o_ = sigf(acc[m][3][r] + biasO);
      float cp = c_prev[idx];
      float cn = cp * f + i_ * g_;
      outH[idx] = o_ * tanh_fast(cn);
      outC[idx] = cn;
    }
  }
}

// ---------------------------------------------------------------------------
extern "C" void kernel_launch(void* const* d_in, const int* in_sizes, int n_in,
                              void* d_out, int out_size, void* d_ws, size_t ws_size,
                              hipStream_t stream) {
  const float* x      = (const float*)d_in[0];
  const float* h_prev = (const float*)d_in[1];
  const float* c_prev = (const float*)d_in[2];
  // d_in[3] = embed (unused by reference forward)
  const float* Wf = (const float*)d_in[4];
  const float* bf = (const float*)d_in[5];
  const float* Wi = (const float*)d_in[6];
  const float* bi = (const float*)d_in[7];
  const float* Wu = (const float*)d_in[8];
  const float* bu = (const float*)d_in[9];
  const float* Wo = (const float*)d_in[10];
  const float* bo = (const float*)d_in[11];

  unsigned short* Apk   = (unsigned short*)d_ws;                                    // 32 MB
  unsigned short* Wfrag = (unsigned short*)((char*)d_ws + (size_t)8192 * 2048 * 2); // 16 MB

  pack_kernel<<<12288, 256, 0, stream>>>(x, h_prev, Wf, Wi, Wu, Wo, Apk, Wfrag);

  float* outH = (float*)d_out;
  float* outC = outH + (size_t)8192 * 1024;
  lstm_gemm_kernel<<<512, 512, 0, stream>>>(Apk, Wfrag, c_prev,
                                            bf, bi, bu, bo, outH, outC);
}